// Round 1
// baseline (209.177 us; speedup 1.0000x reference)
//
#include <hip/hip_runtime.h>
#include <math.h>

// Problem constants (from reference): B=8, T=4096, H=8, D=64, fp32.
#define BB 8
#define TT 4096
#define HH 8
#define DD 64
#define NC 128            // number of T-chunks
#define LL (TT / NC)      // 32 steps per chunk

__device__ __forceinline__ float sigmoidf_(float x) {
    return 1.0f / (1.0f + expf(-x));
}

// Kernel 1: per-(b,chunk) block of 128 threads; thread = (h, d4) handling a
// float4 of the D dimension. Computes chunk aggregate Z (scan with zero init).
__global__ __launch_bounds__(128)
void k_partial(const float4* __restrict__ vals, const float4* __restrict__ aux,
               const float* __restrict__ w, float4* __restrict__ Z) {
    const int blk = blockIdx.x;
    const int b = blk / NC, c = blk % NC;
    const int tid = threadIdx.x;
    const int h = tid >> 4;          // 0..7
    const int d4 = tid & 15;         // 0..15 (float4 index into D=64)

    const float alpha = sigmoidf_(w[h]);
    const float onem  = 1.0f - alpha;
    const float fa    = (onem / fmaxf(onem, 1e-6f)) * alpha;

    const int t0 = c * LL;
    // float4 index: ((b*T + t)*H + h)*D + d -> /4 => (b*T+t)*128 + h*16 + d4
    int base = (b * TT + t0) * 128 + h * 16 + d4;

    float4 y = make_float4(0.f, 0.f, 0.f, 0.f);
#pragma unroll 8
    for (int i = 0; i < LL; ++i) {
        float4 v = vals[base + i * 128];
        float4 a = aux[base + i * 128];
        y.x = alpha * y.x + (onem * v.x + fa * a.x);
        y.y = alpha * y.y + (onem * v.y + fa * a.y);
        y.z = alpha * y.z + (onem * v.z + fa * a.z);
        y.w = alpha * y.w + (onem * v.w + fa * a.w);
    }
    Z[(b * NC + c) * 128 + tid] = y;
}

// Kernel 2: scan carries across chunks. One thread per (b,h,d) = 4096 threads.
// P[c] = state at end of chunk c-1 (carry INTO chunk c); P[0] = v0.
__global__ __launch_bounds__(256)
void k_scan(const float* __restrict__ Z, const float* __restrict__ v0,
            const float* __restrict__ w, float* __restrict__ P) {
    const int g = blockIdx.x * 256 + threadIdx.x;   // 0..4095
    const int b = g >> 9;          // / 512
    const int r = g & 511;         // h*64 + d
    const int h = r >> 6;

    const float alpha = sigmoidf_(w[h]);
    const float aL = powf(alpha, (float)LL);

    float p = v0[r];
    P[(b * NC + 0) * 512 + r] = p;
    for (int c = 1; c < NC; ++c) {
        p = aL * p + Z[(b * NC + (c - 1)) * 512 + r];
        P[(b * NC + c) * 512 + r] = p;
    }
}

// Kernel 3: same traversal as k_partial, seeded with the carry; writes output.
__global__ __launch_bounds__(128)
void k_final(const float4* __restrict__ vals, const float4* __restrict__ aux,
             const float* __restrict__ w, const float4* __restrict__ P,
             float4* __restrict__ out) {
    const int blk = blockIdx.x;
    const int b = blk / NC, c = blk % NC;
    const int tid = threadIdx.x;
    const int h = tid >> 4;
    const int d4 = tid & 15;

    const float alpha = sigmoidf_(w[h]);
    const float onem  = 1.0f - alpha;
    const float fa    = (onem / fmaxf(onem, 1e-6f)) * alpha;

    const int t0 = c * LL;
    int base = (b * TT + t0) * 128 + h * 16 + d4;

    float4 y = P[(b * NC + c) * 128 + tid];
#pragma unroll 8
    for (int i = 0; i < LL; ++i) {
        float4 v = vals[base + i * 128];
        float4 a = aux[base + i * 128];
        y.x = alpha * y.x + (onem * v.x + fa * a.x);
        y.y = alpha * y.y + (onem * v.y + fa * a.y);
        y.z = alpha * y.z + (onem * v.z + fa * a.z);
        y.w = alpha * y.w + (onem * v.w + fa * a.w);
        out[base + i * 128] = y;
    }
}

extern "C" void kernel_launch(void* const* d_in, const int* in_sizes, int n_in,
                              void* d_out, int out_size, void* d_ws, size_t ws_size,
                              hipStream_t stream) {
    const float4* vals = (const float4*)d_in[0];   // values  [B,T,H,D]
    const float4* aux  = (const float4*)d_in[1];   // aux     [B,T,H,D]
    const float*  v0   = (const float*)d_in[2];    // v0      [1,1,H,D] = 512
    const float*  w    = (const float*)d_in[3];    // weight  [H,1] = 8
    float4* out = (float4*)d_out;

    // Workspace: Z then P, each B*NC*512 floats = 2 MB.
    float* Z = (float*)d_ws;
    float* P = Z + (size_t)BB * NC * 512;

    k_partial<<<BB * NC, 128, 0, stream>>>(vals, aux, w, (float4*)Z);
    k_scan<<<(BB * HH * DD) / 256, 256, 0, stream>>>(Z, v0, w, P);
    k_final<<<BB * NC, 128, 0, stream>>>(vals, aux, w, (const float4*)P, out);
}

// Round 2
// 196.521 us; speedup vs baseline: 1.0644x; 1.0644x over previous
//
#include <hip/hip_runtime.h>
#include <math.h>

// B=8, T=4096, H=8, D=64, fp32.
#define BB 8
#define TT 4096
#define HH 8
#define DD 64
#define NC 256            // chunks along T
#define LL (TT / NC)      // 16 steps per chunk

__device__ __forceinline__ float sigmoidf_(float x) {
    return 1.0f / (1.0f + expf(-x));
}

// K1: per-(b,chunk) block of 128 threads (thread = (h,d4), float4 over D).
// Computes zero-init partial scan y0[t], streams it to out, writes chunk
// aggregate Z = y0[L-1].
__global__ __launch_bounds__(128)
void k_partial(const float4* __restrict__ vals, const float4* __restrict__ aux,
               const float* __restrict__ w, float4* __restrict__ out,
               float4* __restrict__ Z) {
    const int blk = blockIdx.x;
    const int b = blk / NC, c = blk % NC;
    const int tid = threadIdx.x;
    const int h = tid >> 4;

    const float alpha = sigmoidf_(w[h]);
    const float onem  = 1.0f - alpha;
    const float fa    = (onem / fmaxf(onem, 1e-6f)) * alpha;

    // float4 index: ((b*T+t)*H + h)*D/4 + d4 = (b*T+t)*128 + tid
    int base = (b * TT + c * LL) * 128 + tid;

    float4 y = make_float4(0.f, 0.f, 0.f, 0.f);
#pragma unroll
    for (int i = 0; i < LL; ++i) {
        float4 v = vals[base + i * 128];
        float4 a = aux[base + i * 128];
        y.x = alpha * y.x + (onem * v.x + fa * a.x);
        y.y = alpha * y.y + (onem * v.y + fa * a.y);
        y.z = alpha * y.z + (onem * v.z + fa * a.z);
        y.w = alpha * y.w + (onem * v.w + fa * a.w);
        out[base + i * 128] = y;
    }
    Z[(b * NC + c) * 128 + tid] = y;
}

// K2: Kogge-Stone scan over the NC chunk aggregates.
// Block = (b, h, d-half): 8*8*2 = 128 blocks, 256 threads (thread = chunk c).
// Each thread owns one chunk row of 32 floats (8 float4 of its d-half).
// Combine: S[c] += aL^off * S[c-off].  P[c] = aL^c * v0 + S_inc[c-1].
__global__ __launch_bounds__(256)
void k_scan(const float4* __restrict__ Z, const float* __restrict__ v0,
            const float* __restrict__ w, float4* __restrict__ P) {
    __shared__ float lds[NC][33];   // +1 pad: stride 33 banks -> conflict-free

    const int blk = blockIdx.x;       // b*16 + h*2 + dh
    const int b  = blk >> 4;
    const int h  = (blk >> 1) & 7;
    const int dh = blk & 1;
    const int r4base = h * 16 + dh * 8;
    const int tid = threadIdx.x;

    const float alpha = sigmoidf_(w[h]);
    const float aL = powf(alpha, (float)LL);

    // Cooperative load: NC*8 = 2048 float4s, 8 per c-row.
#pragma unroll
    for (int it = 0; it < 8; ++it) {
        int idx = it * 256 + tid;
        int c = idx >> 3, k = idx & 7;
        float4 z = Z[(b * NC + c) * 128 + r4base + k];
        lds[c][k * 4 + 0] = z.x;
        lds[c][k * 4 + 1] = z.y;
        lds[c][k * 4 + 2] = z.z;
        lds[c][k * 4 + 3] = z.w;
    }
    __syncthreads();

    const int c = tid;    // thread c owns chunk c's 32-float row
    float s[32];
#pragma unroll
    for (int k = 0; k < 32; ++k) s[k] = lds[c][k];

    float m = aL;
    for (int off = 1; off < NC; off <<= 1) {
        float tmp[32];
        const bool act = (c >= off);
        if (act) {
#pragma unroll
            for (int k = 0; k < 32; ++k) tmp[k] = lds[c - off][k];
        }
        __syncthreads();
        if (act) {
#pragma unroll
            for (int k = 0; k < 32; ++k) { s[k] += m * tmp[k]; lds[c][k] = s[k]; }
        }
        m *= m;
        __syncthreads();
    }

    // Carry into chunk c: P[c] = aL^c * v0 + S_inc[c-1]; P[0] = v0.
    const float pc = powf(alpha, (float)(LL * c));
    const float4* v04 = (const float4*)v0;
#pragma unroll
    for (int k = 0; k < 8; ++k) {
        float4 vv = v04[r4base + k];
        float4 pr;
        if (c == 0) {
            pr = vv;
        } else {
            pr.x = pc * vv.x + lds[c - 1][k * 4 + 0];
            pr.y = pc * vv.y + lds[c - 1][k * 4 + 1];
            pr.z = pc * vv.z + lds[c - 1][k * 4 + 2];
            pr.w = pc * vv.w + lds[c - 1][k * 4 + 3];
        }
        P[(b * NC + c) * 128 + r4base + k] = pr;
    }
}

// K3: elementwise fix-up: out[t] += alpha^(i+1) * P[c]   (t = c*L + i).
// Reads out (L3-hot) + P; no re-read of the 128 MB inputs.
__global__ __launch_bounds__(128)
void k_final(const float* __restrict__ w, const float4* __restrict__ P,
             float4* __restrict__ out) {
    const int blk = blockIdx.x;
    const int b = blk / NC, c = blk % NC;
    const int tid = threadIdx.x;
    const int h = tid >> 4;

    const float alpha = sigmoidf_(w[h]);
    const float4 p = P[(b * NC + c) * 128 + tid];
    int base = (b * TT + c * LL) * 128 + tid;

    float coef = alpha;
#pragma unroll
    for (int i = 0; i < LL; ++i) {
        float4 o = out[base + i * 128];
        o.x += coef * p.x;
        o.y += coef * p.y;
        o.z += coef * p.z;
        o.w += coef * p.w;
        out[base + i * 128] = o;
        coef *= alpha;
    }
}

extern "C" void kernel_launch(void* const* d_in, const int* in_sizes, int n_in,
                              void* d_out, int out_size, void* d_ws, size_t ws_size,
                              hipStream_t stream) {
    const float4* vals = (const float4*)d_in[0];   // values  [B,T,H,D]
    const float4* aux  = (const float4*)d_in[1];   // aux     [B,T,H,D]
    const float*  v0   = (const float*)d_in[2];    // v0      [H,D] = 512
    const float*  w    = (const float*)d_in[3];    // weight  [H] = 8
    float4* out = (float4*)d_out;

    // Workspace: Z then P, each B*NC*128 float4 = 4 MB.
    float4* Z = (float4*)d_ws;
    float4* P = Z + (size_t)BB * NC * 128;

    k_partial<<<BB * NC, 128, 0, stream>>>(vals, aux, w, out, Z);
    k_scan<<<BB * HH * 2, 256, 0, stream>>>(Z, v0, w, P);
    k_final<<<BB * NC, 128, 0, stream>>>(w, P, out);
}